// Round 1
// baseline (403.036 us; speedup 1.0000x reference)
//
#include <hip/hip_runtime.h>
#include <stdint.h>

#define N_CELL 8192
#define N_DRUG 4096
#define E_CELL 262144
#define E_DRUG 131072
#define DOUT   128

typedef float f32x4 __attribute__((ext_vector_type(4)));
typedef short s16x8 __attribute__((ext_vector_type(8)));

// ---------------- workspace layout (float32 element offsets) ----------------
// needs ~14.4 MB of d_ws
#define OFF_DEG_C   0u          // 8192  (becomes dinv in place)
#define OFF_DEG_D   8192u       // 4096
#define OFF_CNT_C   12288u      // 8192  (int)
#define OFF_CNT_D   20480u      // 4096  (int)
#define OFF_CUR_C   24576u      // 8192  (int)
#define OFF_CUR_D   32768u      // 4096  (int)
#define OFF_START_C 36864u      // 8193  (int, padded to 8448)
#define OFF_START_D 45312u      // 4097  (int, padded to 4352)
#define OFF_EW_C    49664u      // 262144
#define OFF_EW_D    311808u     // 131072
#define OFF_SROW_C  442880u     // 262144 (int)
#define OFF_SROW_D  705024u     // 131072 (int)
#define OFF_SCOEF_C 836096u     // 262144
#define OFF_SCOEF_D 1098240u    // 131072
#define OFF_H_C     1229312u    // 8192*128
#define OFF_H_D     2277888u    // 4096*128
#define OFF_END     2802176u
#define WT_C_BYTE   (OFF_END * 4u)                    // bf16 W^T cell: 128*8192*2 B
#define WT_D_BYTE   (WT_C_BYTE + 128u * 8192u * 2u)   // bf16 W^T drug: 128*4096*2 B

__device__ __forceinline__ unsigned short f2bf(float f) {
    union { float f; uint32_t u; } v; v.f = f;
    uint32_t u = v.u + 0x7fffu + ((v.u >> 16) & 1u);   // RNE
    return (unsigned short)(u >> 16);
}

// ---------------- K0: init deg=1 (self loop), cnt=0, cur=0 ----------------
__global__ __launch_bounds__(256) void k_init(float* ws) {
    int i = blockIdx.x * 256 + threadIdx.x;
    if (i >= 36864) return;
    ws[i] = (i < 12288) ? 1.0f : 0.0f;   // [0,12288)=deg:=1 ; cnt/cur int 0 bits
}

// ---------------- K1: ew gather + deg atomic + incoming-edge count ----------------
__global__ __launch_bounds__(256) void k_edge(const float* __restrict__ xc, const int* __restrict__ ec,
                                              const float* __restrict__ xd, const int* __restrict__ ed,
                                              float* __restrict__ ws) {
    int i = blockIdx.x * 256 + threadIdx.x;
    const float* x; const int* edges; float* ew; float* deg; int* cnt; int N, E, idx;
    if (i < E_CELL) {
        idx = i; x = xc; edges = ec; N = N_CELL; E = E_CELL;
        ew = ws + OFF_EW_C; deg = ws + OFF_DEG_C; cnt = (int*)(ws + OFF_CNT_C);
    } else {
        idx = i - E_CELL; if (idx >= E_DRUG) return;
        x = xd; edges = ed; N = N_DRUG; E = E_DRUG;
        ew = ws + OFF_EW_D; deg = ws + OFF_DEG_D; cnt = (int*)(ws + OFF_CNT_D);
    }
    int r = edges[idx], c = edges[E + idx];
    float w = x[(size_t)r * N + c];
    ew[idx] = w;
    atomicAdd(&deg[c], w);
    atomicAdd(&cnt[c], 1);
}

// ---------------- K2: dinv = deg>0 ? rsqrt(max(deg,1e-30)) : 0 (in place) ----------------
__global__ __launch_bounds__(256) void k_dinv(float* ws) {
    int i = blockIdx.x * 256 + threadIdx.x;
    if (i >= 12288) return;
    float d = ws[i];
    ws[i] = d > 0.f ? rsqrtf(fmaxf(d, 1e-30f)) : 0.f;
}

// ---------------- K3: exclusive scan of counts -> start[] (block 0 cell, 1 drug) ----------------
__global__ __launch_bounds__(256) void k_scan(float* ws) {
    const int* cnt; int* start; int N, chunk;
    if (blockIdx.x == 0) { cnt = (const int*)(ws + OFF_CNT_C); start = (int*)(ws + OFF_START_C); N = N_CELL; chunk = 32; }
    else                 { cnt = (const int*)(ws + OFF_CNT_D); start = (int*)(ws + OFF_START_D); N = N_DRUG; chunk = 16; }
    __shared__ int sums[256];
    int t = threadIdx.x, base = t * chunk;
    int s = 0;
    for (int j = 0; j < chunk; ++j) s += cnt[base + j];
    sums[t] = s; __syncthreads();
    for (int off = 1; off < 256; off <<= 1) {
        int v = (t >= off) ? sums[t - off] : 0;
        __syncthreads();
        sums[t] += v;
        __syncthreads();
    }
    int run = sums[t] - s;                 // exclusive prefix
    for (int j = 0; j < chunk; ++j) { start[base + j] = run; run += cnt[base + j]; }
    if (t == 255) start[N] = run;
}

// ---------------- K4: fill CSR slots (srow, scoef) ----------------
__global__ __launch_bounds__(256) void k_fill(const int* __restrict__ ec, const int* __restrict__ ed,
                                              float* __restrict__ ws) {
    int i = blockIdx.x * 256 + threadIdx.x;
    const int* edges; const float* ew; const float* dinv; const int* start;
    int* cur; int* srow; float* scoef; int E, idx;
    if (i < E_CELL) {
        idx = i; edges = ec; E = E_CELL;
        ew = ws + OFF_EW_C; dinv = ws + OFF_DEG_C; start = (const int*)(ws + OFF_START_C);
        cur = (int*)(ws + OFF_CUR_C); srow = (int*)(ws + OFF_SROW_C); scoef = ws + OFF_SCOEF_C;
    } else {
        idx = i - E_CELL; if (idx >= E_DRUG) return;
        edges = ed; E = E_DRUG;
        ew = ws + OFF_EW_D; dinv = ws + OFF_DEG_D; start = (const int*)(ws + OFF_START_D);
        cur = (int*)(ws + OFF_CUR_D); srow = (int*)(ws + OFF_SROW_D); scoef = ws + OFF_SCOEF_D;
    }
    int r = edges[idx], c = edges[E + idx];
    float coef = dinv[r] * ew[idx] * dinv[c];
    int slot = start[c] + atomicAdd(&cur[c], 1);
    srow[slot] = r;
    scoef[slot] = coef;
}

// ---------------- K5: W -> W^T bf16 (32x32 LDS tile transpose) ----------------
__global__ __launch_bounds__(256) void k_wt(const float* __restrict__ Wc, const float* __restrict__ Wd,
                                            unsigned short* __restrict__ wtc, unsigned short* __restrict__ wtd) {
    int bid = blockIdx.x;
    const float* W; unsigned short* wt; int K, tile;
    if (bid < 1024) { W = Wc; wt = wtc; K = N_CELL; tile = bid; }        // 256 x 4 tiles
    else            { W = Wd; wt = wtd; K = N_DRUG; tile = bid - 1024; } // 128 x 4 tiles
    int tk = tile >> 2, tc = tile & 3;
    __shared__ float tl[32][33];
    int t = threadIdx.x, c = t & 31, r8 = t >> 5;
#pragma unroll
    for (int p = 0; p < 4; ++p) {
        int row = r8 + p * 8;
        tl[row][c] = W[(size_t)(tk * 32 + row) * DOUT + tc * 32 + c];
    }
    __syncthreads();
#pragma unroll
    for (int p = 0; p < 4; ++p) {
        int c2 = r8 + p * 8;   // W col (== WT row within tile)
        wt[(size_t)(tc * 32 + c2) * K + tk * 32 + c] = f2bf(tl[c][c2]);
    }
}

// ---------------- K6: h = x @ W via bf16 MFMA ----------------
// tile BM=64 x BN=128 (full), BK=64; 4 waves in 2x2; wave tile 32x64.
// LDS: As[64][64] bf16 (swizzled) + Bs[128][64] bf16 (swizzled) = 24 KB.
__device__ __forceinline__ int swzA(int row, int k) { return ((row << 7) + (k << 1)) ^ ((row & 7) << 4); }
__device__ __forceinline__ int swzB(int col, int k) { return 8192 + (((col << 7) + (k << 1)) ^ ((col & 7) << 4)); }

__global__ __launch_bounds__(256) void k_gemm(const float* __restrict__ xc, const float* __restrict__ xd,
                                              const unsigned short* __restrict__ wtc,
                                              const unsigned short* __restrict__ wtd,
                                              float* __restrict__ ws) {
    int bid = blockIdx.x;
    const float* x; const unsigned short* wt; float* h; int K, brow;
    if (bid < 128) { x = xc; wt = wtc; h = ws + OFF_H_C; K = N_CELL; brow = bid; }
    else           { x = xd; wt = wtd; h = ws + OFF_H_D; K = N_DRUG; brow = bid - 128; }

    __shared__ alignas(16) unsigned char smem[24576];
    int t = threadIdx.x, lane = t & 63, wv = t >> 6;
    int wm = wv >> 1, wn = wv & 1;
    int l15 = lane & 15, l4 = lane >> 4;

    f32x4 acc[2][4] = {};

    int arow = t >> 2, aq = t & 3;                         // A stage: 64 rows x 4 chunks of 16 f32
    const float* abase = x + (size_t)(brow * 64 + arow) * K + aq * 16;

    int ksteps = K >> 6;
    for (int kt = 0; kt < ksteps; ++kt) {
        // ---- stage A: 64x64 f32 -> bf16, swizzled ----
        const float4* p = (const float4*)(abase + kt * 64);
        float4 q0 = p[0], q1 = p[1], q2 = p[2], q3 = p[3];
        s16x8 lo, hi;
        lo[0] = (short)f2bf(q0.x); lo[1] = (short)f2bf(q0.y); lo[2] = (short)f2bf(q0.z); lo[3] = (short)f2bf(q0.w);
        lo[4] = (short)f2bf(q1.x); lo[5] = (short)f2bf(q1.y); lo[6] = (short)f2bf(q1.z); lo[7] = (short)f2bf(q1.w);
        hi[0] = (short)f2bf(q2.x); hi[1] = (short)f2bf(q2.y); hi[2] = (short)f2bf(q2.z); hi[3] = (short)f2bf(q2.w);
        hi[4] = (short)f2bf(q3.x); hi[5] = (short)f2bf(q3.y); hi[6] = (short)f2bf(q3.z); hi[7] = (short)f2bf(q3.w);
        *(s16x8*)&smem[swzA(arow, aq * 16)]     = lo;
        *(s16x8*)&smem[swzA(arow, aq * 16 + 8)] = hi;
        // ---- stage B: 128 cols x 64 k bf16 from WT, swizzled ----
#pragma unroll
        for (int jj = 0; jj < 4; ++jj) {
            int flat = t + jj * 256;
            int c = flat >> 3, j = flat & 7;
            s16x8 bv = *(const s16x8*)(wt + (size_t)c * K + kt * 64 + j * 8);
            *(s16x8*)&smem[swzB(c, j * 8)] = bv;
        }
        __syncthreads();
        // ---- compute: 16 MFMA per wave ----
#pragma unroll
        for (int kk = 0; kk < 2; ++kk) {
            int kb = kk * 32 + l4 * 8;
            s16x8 a[2], b[4];
#pragma unroll
            for (int m = 0; m < 2; ++m)
                a[m] = *(const s16x8*)&smem[swzA(wm * 32 + m * 16 + l15, kb)];
#pragma unroll
            for (int n = 0; n < 4; ++n)
                b[n] = *(const s16x8*)&smem[swzB(wn * 64 + n * 16 + l15, kb)];
#pragma unroll
            for (int m = 0; m < 2; ++m)
#pragma unroll
                for (int n = 0; n < 4; ++n)
                    acc[m][n] = __builtin_amdgcn_mfma_f32_16x16x32_bf16(a[m], b[n], acc[m][n], 0, 0, 0);
        }
        __syncthreads();
    }
    // ---- epilogue: D layout col=lane&15, row=(lane>>4)*4+j ----
#pragma unroll
    for (int m = 0; m < 2; ++m)
#pragma unroll
        for (int n = 0; n < 4; ++n) {
            int col  = wn * 64 + n * 16 + l15;
            int row0 = wm * 32 + m * 16 + l4 * 4;
#pragma unroll
            for (int j = 0; j < 4; ++j)
                h[(size_t)(brow * 64 + row0 + j) * DOUT + col] = acc[m][n][j];
        }
}

// ---------------- K7: CSR gather + self loop + bias + relu ----------------
__global__ __launch_bounds__(256) void k_gather(const float* __restrict__ ws,
                                                const float* __restrict__ bc, const float* __restrict__ bd,
                                                float* __restrict__ out) {
    int wv = threadIdx.x >> 6, lane = threadIdx.x & 63;
    int g = blockIdx.x * 4 + wv;
    const float* h; const int* srow; const float* scoef; const int* start; const float* dinv;
    const float* bvec; float* outp; int node;
    if (g < N_CELL) {
        node = g; h = ws + OFF_H_C; srow = (const int*)(ws + OFF_SROW_C); scoef = ws + OFF_SCOEF_C;
        start = (const int*)(ws + OFF_START_C); dinv = ws + OFF_DEG_C; bvec = bc; outp = out;
    } else {
        node = g - N_CELL; if (node >= N_DRUG) return;
        h = ws + OFF_H_D; srow = (const int*)(ws + OFF_SROW_D); scoef = ws + OFF_SCOEF_D;
        start = (const int*)(ws + OFF_START_D); dinv = ws + OFF_DEG_D; bvec = bd;
        outp = out + (size_t)N_CELL * DOUT;
    }
    float di = dinv[node], sc = di * di;
    float2 v = ((const float2*)(h + (size_t)node * DOUT))[lane];
    float ax = sc * v.x, ay = sc * v.y;
    int s0 = start[node], s1 = start[node + 1];
    int e = s0;
    for (; e + 1 < s1; e += 2) {
        int r0 = srow[e];     float c0 = scoef[e];
        int r1 = srow[e + 1]; float c1 = scoef[e + 1];
        float2 u0 = ((const float2*)(h + (size_t)r0 * DOUT))[lane];
        float2 u1 = ((const float2*)(h + (size_t)r1 * DOUT))[lane];
        ax += c0 * u0.x + c1 * u1.x;
        ay += c0 * u0.y + c1 * u1.y;
    }
    if (e < s1) {
        int r = srow[e]; float cf = scoef[e];
        float2 u = ((const float2*)(h + (size_t)r * DOUT))[lane];
        ax += cf * u.x; ay += cf * u.y;
    }
    float2 bb = ((const float2*)bvec)[lane];
    ax = fmaxf(ax + bb.x, 0.f);
    ay = fmaxf(ay + bb.y, 0.f);
    float2 o; o.x = ax; o.y = ay;
    ((float2*)outp)[(size_t)node * 64 + lane] = o;
}

// ---------------- host ----------------
extern "C" void kernel_launch(void* const* d_in, const int* in_sizes, int n_in,
                              void* d_out, int out_size, void* d_ws, size_t ws_size,
                              hipStream_t stream) {
    const float* cell_feat = (const float*)d_in[0];
    const int*   cell_edge = (const int*)d_in[1];
    const float* W_cell    = (const float*)d_in[2];
    const float* b_cell    = (const float*)d_in[3];
    const float* drug_feat = (const float*)d_in[4];
    const int*   drug_edge = (const int*)d_in[5];
    const float* W_drug    = (const float*)d_in[6];
    const float* b_drug    = (const float*)d_in[7];
    float* out = (float*)d_out;
    float* ws  = (float*)d_ws;
    unsigned short* wtc = (unsigned short*)((char*)d_ws + WT_C_BYTE);
    unsigned short* wtd = (unsigned short*)((char*)d_ws + WT_D_BYTE);

    k_init<<<144, 256, 0, stream>>>(ws);
    k_edge<<<(E_CELL + E_DRUG) / 256, 256, 0, stream>>>(cell_feat, cell_edge, drug_feat, drug_edge, ws);
    k_dinv<<<48, 256, 0, stream>>>(ws);
    k_scan<<<2, 256, 0, stream>>>(ws);
    k_wt<<<1536, 256, 0, stream>>>(W_cell, W_drug, wtc, wtd);
    k_fill<<<1536, 256, 0, stream>>>(cell_edge, drug_edge, ws);
    k_gemm<<<192, 256, 0, stream>>>(cell_feat, drug_feat, wtc, wtd, ws);
    k_gather<<<3072, 256, 0, stream>>>(ws, b_cell, b_drug, out);
}

// Round 2
// 216.923 us; speedup vs baseline: 1.8580x; 1.8580x over previous
//
#include <hip/hip_runtime.h>
#include <stdint.h>

#define N_CELL 8192
#define N_DRUG 4096
#define E_CELL 262144
#define E_DRUG 131072
#define DOUT   128

typedef float f32x4 __attribute__((ext_vector_type(4)));
typedef short s16x8 __attribute__((ext_vector_type(8)));

// ---------------- workspace layout (float32 element offsets) ----------------
// needs ~14.4 MB of d_ws
#define OFF_DEG_C   0u          // 8192  (becomes dinv in place)
#define OFF_DEG_D   8192u       // 4096
#define OFF_CNT_C   12288u      // 8192  (int)
#define OFF_CNT_D   20480u      // 4096  (int)
#define OFF_CUR_C   24576u      // 8192  (int)
#define OFF_CUR_D   32768u      // 4096  (int)
#define OFF_START_C 36864u      // 8193  (int, padded to 8448)
#define OFF_START_D 45312u      // 4097  (int, padded to 4352)
#define OFF_EW_C    49664u      // 262144
#define OFF_EW_D    311808u     // 131072
#define OFF_SROW_C  442880u     // 262144 (int)
#define OFF_SROW_D  705024u     // 131072 (int)
#define OFF_SCOEF_C 836096u     // 262144
#define OFF_SCOEF_D 1098240u    // 131072
#define OFF_H_C     1229312u    // 8192*128
#define OFF_H_D     2277888u    // 4096*128
#define OFF_END     2802176u
#define WT_C_BYTE   (OFF_END * 4u)                    // bf16 W^T cell: 128*8192*2 B
#define WT_D_BYTE   (WT_C_BYTE + 128u * 8192u * 2u)   // bf16 W^T drug: 128*4096*2 B

__device__ __forceinline__ unsigned short f2bf(float f) {
    union { float f; uint32_t u; } v; v.f = f;
    uint32_t u = v.u + 0x7fffu + ((v.u >> 16) & 1u);   // RNE
    return (unsigned short)(u >> 16);
}

__device__ __forceinline__ s16x8 cvt8(float4 a, float4 b) {
    s16x8 r;
    r[0] = (short)f2bf(a.x); r[1] = (short)f2bf(a.y); r[2] = (short)f2bf(a.z); r[3] = (short)f2bf(a.w);
    r[4] = (short)f2bf(b.x); r[5] = (short)f2bf(b.y); r[6] = (short)f2bf(b.z); r[7] = (short)f2bf(b.w);
    return r;
}

// ---------------- K0: init deg=1 (self loop), cnt=0, cur=0 ----------------
__global__ __launch_bounds__(256) void k_init(float* ws) {
    int i = blockIdx.x * 256 + threadIdx.x;
    if (i >= 36864) return;
    ws[i] = (i < 12288) ? 1.0f : 0.0f;   // [0,12288)=deg:=1 ; cnt/cur int 0 bits
}

// ---------------- K1: ew gather + deg atomic + incoming-edge count ----------------
__global__ __launch_bounds__(256) void k_edge(const float* __restrict__ xc, const int* __restrict__ ec,
                                              const float* __restrict__ xd, const int* __restrict__ ed,
                                              float* __restrict__ ws) {
    int i = blockIdx.x * 256 + threadIdx.x;
    const float* x; const int* edges; float* ew; float* deg; int* cnt; int N, E, idx;
    if (i < E_CELL) {
        idx = i; x = xc; edges = ec; N = N_CELL; E = E_CELL;
        ew = ws + OFF_EW_C; deg = ws + OFF_DEG_C; cnt = (int*)(ws + OFF_CNT_C);
    } else {
        idx = i - E_CELL; if (idx >= E_DRUG) return;
        x = xd; edges = ed; N = N_DRUG; E = E_DRUG;
        ew = ws + OFF_EW_D; deg = ws + OFF_DEG_D; cnt = (int*)(ws + OFF_CNT_D);
    }
    int r = edges[idx], c = edges[E + idx];
    float w = x[(size_t)r * N + c];
    ew[idx] = w;
    unsafeAtomicAdd(&deg[c], w);
    atomicAdd(&cnt[c], 1);
}

// ---------------- K2: dinv = deg>0 ? rsqrt(max(deg,1e-30)) : 0 (in place) ----------------
__global__ __launch_bounds__(256) void k_dinv(float* ws) {
    int i = blockIdx.x * 256 + threadIdx.x;
    if (i >= 12288) return;
    float d = ws[i];
    ws[i] = d > 0.f ? rsqrtf(fmaxf(d, 1e-30f)) : 0.f;
}

// ---------------- K3: exclusive scan of counts -> start[] (block 0 cell, 1 drug) ----------------
__global__ __launch_bounds__(256) void k_scan(float* ws) {
    const int* cnt; int* start; int N, chunk;
    if (blockIdx.x == 0) { cnt = (const int*)(ws + OFF_CNT_C); start = (int*)(ws + OFF_START_C); N = N_CELL; chunk = 32; }
    else                 { cnt = (const int*)(ws + OFF_CNT_D); start = (int*)(ws + OFF_START_D); N = N_DRUG; chunk = 16; }
    __shared__ int sums[256];
    int t = threadIdx.x, base = t * chunk;
    int s = 0;
    for (int j = 0; j < chunk; ++j) s += cnt[base + j];
    sums[t] = s; __syncthreads();
    for (int off = 1; off < 256; off <<= 1) {
        int v = (t >= off) ? sums[t - off] : 0;
        __syncthreads();
        sums[t] += v;
        __syncthreads();
    }
    int run = sums[t] - s;                 // exclusive prefix
    for (int j = 0; j < chunk; ++j) { start[base + j] = run; run += cnt[base + j]; }
    if (t == 255) start[N] = run;
}

// ---------------- K4: fill CSR slots (srow, scoef) ----------------
__global__ __launch_bounds__(256) void k_fill(const int* __restrict__ ec, const int* __restrict__ ed,
                                              float* __restrict__ ws) {
    int i = blockIdx.x * 256 + threadIdx.x;
    const int* edges; const float* ew; const float* dinv; const int* start;
    int* cur; int* srow; float* scoef; int E, idx;
    if (i < E_CELL) {
        idx = i; edges = ec; E = E_CELL;
        ew = ws + OFF_EW_C; dinv = ws + OFF_DEG_C; start = (const int*)(ws + OFF_START_C);
        cur = (int*)(ws + OFF_CUR_C); srow = (int*)(ws + OFF_SROW_C); scoef = ws + OFF_SCOEF_C;
    } else {
        idx = i - E_CELL; if (idx >= E_DRUG) return;
        edges = ed; E = E_DRUG;
        ew = ws + OFF_EW_D; dinv = ws + OFF_DEG_D; start = (const int*)(ws + OFF_START_D);
        cur = (int*)(ws + OFF_CUR_D); srow = (int*)(ws + OFF_SROW_D); scoef = ws + OFF_SCOEF_D;
    }
    int r = edges[idx], c = edges[E + idx];
    float coef = dinv[r] * ew[idx] * dinv[c];
    int slot = start[c] + atomicAdd(&cur[c], 1);
    srow[slot] = r;
    scoef[slot] = coef;
}

// ---------------- K5: W -> W^T bf16 (32x32 LDS tile transpose) ----------------
__global__ __launch_bounds__(256) void k_wt(const float* __restrict__ Wc, const float* __restrict__ Wd,
                                            unsigned short* __restrict__ wtc, unsigned short* __restrict__ wtd) {
    int bid = blockIdx.x;
    const float* W; unsigned short* wt; int K, tile;
    if (bid < 1024) { W = Wc; wt = wtc; K = N_CELL; tile = bid; }        // 256 x 4 tiles
    else            { W = Wd; wt = wtd; K = N_DRUG; tile = bid - 1024; } // 128 x 4 tiles
    int tk = tile >> 2, tc = tile & 3;
    __shared__ float tl[32][33];
    int t = threadIdx.x, c = t & 31, r8 = t >> 5;
#pragma unroll
    for (int p = 0; p < 4; ++p) {
        int row = r8 + p * 8;
        tl[row][c] = W[(size_t)(tk * 32 + row) * DOUT + tc * 32 + c];
    }
    __syncthreads();
#pragma unroll
    for (int p = 0; p < 4; ++p) {
        int c2 = r8 + p * 8;   // W col (== WT row within tile)
        wt[(size_t)(tc * 32 + c2) * K + tk * 32 + c] = f2bf(tl[c][c2]);
    }
}

// ---------------- K6: h = x @ W via bf16 MFMA, K-split for parallelism ----------------
// tile BM=64 x BN=128 (full), BK=64; K-chunk CK=1024 (16 BK-steps/block).
// grid = 8192/64 * 8  +  4096/64 * 4 = 1024 + 256 = 1280 blocks = 5 blocks/CU.
// Each block accumulates its partial 64x128 tile into pre-zeroed h via HW f32 atomics.
// 4 waves in 2x2; wave tile 32x64. LDS: As[64][64] + Bs[128][64] bf16 swizzled = 24 KB.
// 1-deep register prefetch: next tile's global loads issued before the MFMA cluster.
__device__ __forceinline__ int swzA(int row, int k) { return ((row << 7) + (k << 1)) ^ ((row & 7) << 4); }
__device__ __forceinline__ int swzB(int col, int k) { return 8192 + (((col << 7) + (k << 1)) ^ ((col & 7) << 4)); }

__global__ __launch_bounds__(256) void k_gemm(const float* __restrict__ xc, const float* __restrict__ xd,
                                              const unsigned short* __restrict__ wtc,
                                              const unsigned short* __restrict__ wtd,
                                              float* __restrict__ ws) {
    int bid = blockIdx.x;
    const float* x; const unsigned short* wt; float* h; int K, mt, ch;
    if (bid < 1024) { x = xc; wt = wtc; h = ws + OFF_H_C; K = N_CELL; mt = bid >> 3; ch = bid & 7; }
    else { int b = bid - 1024; x = xd; wt = wtd; h = ws + OFF_H_D; K = N_DRUG; mt = b >> 2; ch = b & 3; }
    int k0 = ch << 10;                                   // K-chunk base

    __shared__ alignas(16) unsigned char smem[24576];
    int t = threadIdx.x, lane = t & 63, wv = t >> 6;
    int wm = wv >> 1, wn = wv & 1;
    int l15 = lane & 15, l4 = lane >> 4;

    f32x4 acc[2][4] = {};

    int arow = t >> 2, aq = t & 3;                       // A stage: 64 rows x 4 chunks of 16 f32
    const float* aptr = x + (size_t)(mt * 64 + arow) * K + k0 + aq * 16;

    float4 qa[4];          // prefetched A (16 f32)
    s16x8  qb[4];          // prefetched B (4 x 8 bf16)

#define LOADA(KT) { const float4* p = (const float4*)(aptr + (KT) * 64); \
                    qa[0] = p[0]; qa[1] = p[1]; qa[2] = p[2]; qa[3] = p[3]; }
#define LOADB(KT) { _Pragma("unroll") for (int jj = 0; jj < 4; ++jj) { \
                    int flat = t + jj * 256; int c = flat >> 3, j = flat & 7; \
                    qb[jj] = *(const s16x8*)(wt + (size_t)c * K + k0 + (KT) * 64 + j * 8); } }

    LOADA(0); LOADB(0);
#pragma unroll 1
    for (int kt = 0; kt < 16; ++kt) {
        // ---- write staged tile to LDS (A converted f32->bf16), swizzled ----
        *(s16x8*)&smem[swzA(arow, aq * 16)]     = cvt8(qa[0], qa[1]);
        *(s16x8*)&smem[swzA(arow, aq * 16 + 8)] = cvt8(qa[2], qa[3]);
#pragma unroll
        for (int jj = 0; jj < 4; ++jj) {
            int flat = t + jj * 256;
            int c = flat >> 3, j = flat & 7;
            *(s16x8*)&smem[swzB(c, j * 8)] = qb[jj];
        }
        __syncthreads();
        // ---- issue next tile's loads (latency hides under MFMA + other waves) ----
        if (kt < 15) { LOADA(kt + 1); LOADB(kt + 1); }
        // ---- compute: 16 MFMA per wave ----
#pragma unroll
        for (int kk = 0; kk < 2; ++kk) {
            int kb = kk * 32 + l4 * 8;
            s16x8 a[2], b[4];
#pragma unroll
            for (int m = 0; m < 2; ++m)
                a[m] = *(const s16x8*)&smem[swzA(wm * 32 + m * 16 + l15, kb)];
#pragma unroll
            for (int n = 0; n < 4; ++n)
                b[n] = *(const s16x8*)&smem[swzB(wn * 64 + n * 16 + l15, kb)];
#pragma unroll
            for (int m = 0; m < 2; ++m)
#pragma unroll
                for (int n = 0; n < 4; ++n)
                    acc[m][n] = __builtin_amdgcn_mfma_f32_16x16x32_bf16(a[m], b[n], acc[m][n], 0, 0, 0);
        }
        __syncthreads();
    }
#undef LOADA
#undef LOADB
    // ---- epilogue: accumulate partial tile. D layout col=lane&15, row=(lane>>4)*4+j ----
#pragma unroll
    for (int m = 0; m < 2; ++m)
#pragma unroll
        for (int n = 0; n < 4; ++n) {
            int col  = wn * 64 + n * 16 + l15;
            int row0 = mt * 64 + wm * 32 + m * 16 + l4 * 4;
#pragma unroll
            for (int j = 0; j < 4; ++j)
                unsafeAtomicAdd(&h[(size_t)(row0 + j) * DOUT + col], acc[m][n][j]);
        }
}

// ---------------- K7: CSR gather + self loop + bias + relu ----------------
__global__ __launch_bounds__(256) void k_gather(const float* __restrict__ ws,
                                                const float* __restrict__ bc, const float* __restrict__ bd,
                                                float* __restrict__ out) {
    int wv = threadIdx.x >> 6, lane = threadIdx.x & 63;
    int g = blockIdx.x * 4 + wv;
    const float* h; const int* srow; const float* scoef; const int* start; const float* dinv;
    const float* bvec; float* outp; int node;
    if (g < N_CELL) {
        node = g; h = ws + OFF_H_C; srow = (const int*)(ws + OFF_SROW_C); scoef = ws + OFF_SCOEF_C;
        start = (const int*)(ws + OFF_START_C); dinv = ws + OFF_DEG_C; bvec = bc; outp = out;
    } else {
        node = g - N_CELL; if (node >= N_DRUG) return;
        h = ws + OFF_H_D; srow = (const int*)(ws + OFF_SROW_D); scoef = ws + OFF_SCOEF_D;
        start = (const int*)(ws + OFF_START_D); dinv = ws + OFF_DEG_D; bvec = bd;
        outp = out + (size_t)N_CELL * DOUT;
    }
    float di = dinv[node], sc = di * di;
    float2 v = ((const float2*)(h + (size_t)node * DOUT))[lane];
    float ax = sc * v.x, ay = sc * v.y;
    int s0 = start[node], s1 = start[node + 1];
    int e = s0;
    for (; e + 1 < s1; e += 2) {
        int r0 = srow[e];     float c0 = scoef[e];
        int r1 = srow[e + 1]; float c1 = scoef[e + 1];
        float2 u0 = ((const float2*)(h + (size_t)r0 * DOUT))[lane];
        float2 u1 = ((const float2*)(h + (size_t)r1 * DOUT))[lane];
        ax += c0 * u0.x + c1 * u1.x;
        ay += c0 * u0.y + c1 * u1.y;
    }
    if (e < s1) {
        int r = srow[e]; float cf = scoef[e];
        float2 u = ((const float2*)(h + (size_t)r * DOUT))[lane];
        ax += cf * u.x; ay += cf * u.y;
    }
    float2 bb = ((const float2*)bvec)[lane];
    ax = fmaxf(ax + bb.x, 0.f);
    ay = fmaxf(ay + bb.y, 0.f);
    float2 o; o.x = ax; o.y = ay;
    ((float2*)outp)[(size_t)node * 64 + lane] = o;
}

// ---------------- host ----------------
extern "C" void kernel_launch(void* const* d_in, const int* in_sizes, int n_in,
                              void* d_out, int out_size, void* d_ws, size_t ws_size,
                              hipStream_t stream) {
    const float* cell_feat = (const float*)d_in[0];
    const int*   cell_edge = (const int*)d_in[1];
    const float* W_cell    = (const float*)d_in[2];
    const float* b_cell    = (const float*)d_in[3];
    const float* drug_feat = (const float*)d_in[4];
    const int*   drug_edge = (const int*)d_in[5];
    const float* W_drug    = (const float*)d_in[6];
    const float* b_drug    = (const float*)d_in[7];
    float* out = (float*)d_out;
    float* ws  = (float*)d_ws;
    unsigned short* wtc = (unsigned short*)((char*)d_ws + WT_C_BYTE);
    unsigned short* wtd = (unsigned short*)((char*)d_ws + WT_D_BYTE);

    k_init<<<144, 256, 0, stream>>>(ws);
    // zero h (gemm accumulates into it atomically; must re-zero every call)
    hipMemsetAsync((char*)d_ws + OFF_H_C * 4u, 0, (OFF_END - OFF_H_C) * 4u, stream);
    k_edge<<<(E_CELL + E_DRUG) / 256, 256, 0, stream>>>(cell_feat, cell_edge, drug_feat, drug_edge, ws);
    k_dinv<<<48, 256, 0, stream>>>(ws);
    k_scan<<<2, 256, 0, stream>>>(ws);
    k_wt<<<1536, 256, 0, stream>>>(W_cell, W_drug, wtc, wtd);
    k_fill<<<1536, 256, 0, stream>>>(cell_edge, drug_edge, ws);
    k_gemm<<<1280, 256, 0, stream>>>(cell_feat, drug_feat, wtc, wtd, ws);
    k_gather<<<3072, 256, 0, stream>>>(ws, b_cell, b_drug, out);
}

// Round 3
// 216.740 us; speedup vs baseline: 1.8595x; 1.0008x over previous
//
#include <hip/hip_runtime.h>
#include <stdint.h>

#define N_CELL 8192
#define N_DRUG 4096
#define E_CELL 262144
#define E_DRUG 131072
#define DOUT   128

typedef float f32x4 __attribute__((ext_vector_type(4)));
typedef short s16x8 __attribute__((ext_vector_type(8)));

// ---------------- workspace layout (float32 element offsets) ----------------
// needs ~14.4 MB of d_ws
#define OFF_DEG_C   0u          // 8192  (becomes dinv in place)
#define OFF_DEG_D   8192u       // 4096
#define OFF_CNT_C   12288u      // 8192  (int)
#define OFF_CNT_D   20480u      // 4096  (int)
#define OFF_CUR_C   24576u      // 8192  (int)
#define OFF_CUR_D   32768u      // 4096  (int)
#define OFF_START_C 36864u      // 8193  (int, padded to 8448)
#define OFF_START_D 45312u      // 4097  (int, padded to 4352)
#define OFF_EW_C    49664u      // 262144
#define OFF_EW_D    311808u     // 131072
#define OFF_SROW_C  442880u     // 262144 (int)
#define OFF_SROW_D  705024u     // 131072 (int)
#define OFF_SCOEF_C 836096u     // 262144
#define OFF_SCOEF_D 1098240u    // 131072
#define OFF_H_C     1229312u    // 8192*128
#define OFF_H_D     2277888u    // 4096*128
#define OFF_END     2802176u
#define WT_C_BYTE   (OFF_END * 4u)                    // bf16 W^T cell: 128*8192*2 B
#define WT_D_BYTE   (WT_C_BYTE + 128u * 8192u * 2u)   // bf16 W^T drug: 128*4096*2 B

__device__ __forceinline__ unsigned short f2bf(float f) {
    union { float f; uint32_t u; } v; v.f = f;
    uint32_t u = v.u + 0x7fffu + ((v.u >> 16) & 1u);   // RNE
    return (unsigned short)(u >> 16);
}

__device__ __forceinline__ s16x8 cvt8(float4 a, float4 b) {
    s16x8 r;
    r[0] = (short)f2bf(a.x); r[1] = (short)f2bf(a.y); r[2] = (short)f2bf(a.z); r[3] = (short)f2bf(a.w);
    r[4] = (short)f2bf(b.x); r[5] = (short)f2bf(b.y); r[6] = (short)f2bf(b.z); r[7] = (short)f2bf(b.w);
    return r;
}

// ---------------- K0: init deg=1 (self loop), cnt=0, cur=0 ----------------
__global__ __launch_bounds__(256) void k_init(float* ws) {
    int i = blockIdx.x * 256 + threadIdx.x;
    if (i >= 36864) return;
    ws[i] = (i < 12288) ? 1.0f : 0.0f;   // [0,12288)=deg:=1 ; cnt/cur int 0 bits
}

// ---------------- K0b: zero h (gemm accumulates atomically; re-zero every call) ----
// 1536 blocks x 256 threads x 1 float4 = 1,572,864 floats = h_c + h_d exactly.
__global__ __launch_bounds__(256) void k_zero(float* ws) {
    size_t i = (size_t)blockIdx.x * 256 + threadIdx.x;
    ((float4*)(ws + OFF_H_C))[i] = make_float4(0.f, 0.f, 0.f, 0.f);
}

// ---------------- K1: ew gather + deg atomic + incoming-edge count ----------------
__global__ __launch_bounds__(256) void k_edge(const float* __restrict__ xc, const int* __restrict__ ec,
                                              const float* __restrict__ xd, const int* __restrict__ ed,
                                              float* __restrict__ ws) {
    int i = blockIdx.x * 256 + threadIdx.x;
    const float* x; const int* edges; float* ew; float* deg; int* cnt; int N, E, idx;
    if (i < E_CELL) {
        idx = i; x = xc; edges = ec; N = N_CELL; E = E_CELL;
        ew = ws + OFF_EW_C; deg = ws + OFF_DEG_C; cnt = (int*)(ws + OFF_CNT_C);
    } else {
        idx = i - E_CELL; if (idx >= E_DRUG) return;
        x = xd; edges = ed; N = N_DRUG; E = E_DRUG;
        ew = ws + OFF_EW_D; deg = ws + OFF_DEG_D; cnt = (int*)(ws + OFF_CNT_D);
    }
    int r = edges[idx], c = edges[E + idx];
    float w = x[(size_t)r * N + c];
    ew[idx] = w;
    unsafeAtomicAdd(&deg[c], w);
    atomicAdd(&cnt[c], 1);
}

// ---------------- K2: dinv = deg>0 ? rsqrt(max(deg,1e-30)) : 0 (in place) ----------------
__global__ __launch_bounds__(256) void k_dinv(float* ws) {
    int i = blockIdx.x * 256 + threadIdx.x;
    if (i >= 12288) return;
    float d = ws[i];
    ws[i] = d > 0.f ? rsqrtf(fmaxf(d, 1e-30f)) : 0.f;
}

// ---------------- K3: exclusive scan of counts -> start[] (block 0 cell, 1 drug) ----------------
__global__ __launch_bounds__(256) void k_scan(float* ws) {
    const int* cnt; int* start; int N, chunk;
    if (blockIdx.x == 0) { cnt = (const int*)(ws + OFF_CNT_C); start = (int*)(ws + OFF_START_C); N = N_CELL; chunk = 32; }
    else                 { cnt = (const int*)(ws + OFF_CNT_D); start = (int*)(ws + OFF_START_D); N = N_DRUG; chunk = 16; }
    __shared__ int sums[256];
    int t = threadIdx.x, base = t * chunk;
    int s = 0;
    for (int j = 0; j < chunk; ++j) s += cnt[base + j];
    sums[t] = s; __syncthreads();
    for (int off = 1; off < 256; off <<= 1) {
        int v = (t >= off) ? sums[t - off] : 0;
        __syncthreads();
        sums[t] += v;
        __syncthreads();
    }
    int run = sums[t] - s;                 // exclusive prefix
    for (int j = 0; j < chunk; ++j) { start[base + j] = run; run += cnt[base + j]; }
    if (t == 255) start[N] = run;
}

// ---------------- K4: fill CSR slots (srow, scoef) ----------------
__global__ __launch_bounds__(256) void k_fill(const int* __restrict__ ec, const int* __restrict__ ed,
                                              float* __restrict__ ws) {
    int i = blockIdx.x * 256 + threadIdx.x;
    const int* edges; const float* ew; const float* dinv; const int* start;
    int* cur; int* srow; float* scoef; int E, idx;
    if (i < E_CELL) {
        idx = i; edges = ec; E = E_CELL;
        ew = ws + OFF_EW_C; dinv = ws + OFF_DEG_C; start = (const int*)(ws + OFF_START_C);
        cur = (int*)(ws + OFF_CUR_C); srow = (int*)(ws + OFF_SROW_C); scoef = ws + OFF_SCOEF_C;
    } else {
        idx = i - E_CELL; if (idx >= E_DRUG) return;
        edges = ed; E = E_DRUG;
        ew = ws + OFF_EW_D; dinv = ws + OFF_DEG_D; start = (const int*)(ws + OFF_START_D);
        cur = (int*)(ws + OFF_CUR_D); srow = (int*)(ws + OFF_SROW_D); scoef = ws + OFF_SCOEF_D;
    }
    int r = edges[idx], c = edges[E + idx];
    float coef = dinv[r] * ew[idx] * dinv[c];
    int slot = start[c] + atomicAdd(&cur[c], 1);
    srow[slot] = r;
    scoef[slot] = coef;
}

// ---------------- K5: W -> W^T bf16 (32x32 LDS tile transpose) ----------------
__global__ __launch_bounds__(256) void k_wt(const float* __restrict__ Wc, const float* __restrict__ Wd,
                                            unsigned short* __restrict__ wtc, unsigned short* __restrict__ wtd) {
    int bid = blockIdx.x;
    const float* W; unsigned short* wt; int K, tile;
    if (bid < 1024) { W = Wc; wt = wtc; K = N_CELL; tile = bid; }        // 256 x 4 tiles
    else            { W = Wd; wt = wtd; K = N_DRUG; tile = bid - 1024; } // 128 x 4 tiles
    int tk = tile >> 2, tc = tile & 3;
    __shared__ float tl[32][33];
    int t = threadIdx.x, c = t & 31, r8 = t >> 5;
#pragma unroll
    for (int p = 0; p < 4; ++p) {
        int row = r8 + p * 8;
        tl[row][c] = W[(size_t)(tk * 32 + row) * DOUT + tc * 32 + c];
    }
    __syncthreads();
#pragma unroll
    for (int p = 0; p < 4; ++p) {
        int c2 = r8 + p * 8;   // W col (== WT row within tile)
        wt[(size_t)(tc * 32 + c2) * K + tk * 32 + c] = f2bf(tl[c][c2]);
    }
}

// ---------------- K6: h = x @ W via bf16 MFMA, K-split for parallelism ----------------
// tile BM=64 x BN=128 (full), BK=64; K-chunk CK=1024 (16 BK-steps/block).
// grid = 8192/64 * 8  +  4096/64 * 4 = 1024 + 256 = 1280 blocks = 5 blocks/CU.
// Each block accumulates its partial 64x128 tile into pre-zeroed h via HW f32 atomics.
// 4 waves in 2x2; wave tile 32x64. LDS: As[64][64] + Bs[128][64] bf16 swizzled = 24 KB.
// 1-deep register prefetch: next tile's global loads issued before the MFMA cluster.
__device__ __forceinline__ int swzA(int row, int k) { return ((row << 7) + (k << 1)) ^ ((row & 7) << 4); }
__device__ __forceinline__ int swzB(int col, int k) { return 8192 + (((col << 7) + (k << 1)) ^ ((col & 7) << 4)); }

__global__ __launch_bounds__(256) void k_gemm(const float* __restrict__ xc, const float* __restrict__ xd,
                                              const unsigned short* __restrict__ wtc,
                                              const unsigned short* __restrict__ wtd,
                                              float* __restrict__ ws) {
    int bid = blockIdx.x;
    const float* x; const unsigned short* wt; float* h; int K, mt, ch;
    if (bid < 1024) { x = xc; wt = wtc; h = ws + OFF_H_C; K = N_CELL; mt = bid >> 3; ch = bid & 7; }
    else { int b = bid - 1024; x = xd; wt = wtd; h = ws + OFF_H_D; K = N_DRUG; mt = b >> 2; ch = b & 3; }
    int k0 = ch << 10;                                   // K-chunk base

    __shared__ alignas(16) unsigned char smem[24576];
    int t = threadIdx.x, lane = t & 63, wv = t >> 6;
    int wm = wv >> 1, wn = wv & 1;
    int l15 = lane & 15, l4 = lane >> 4;

    f32x4 acc[2][4] = {};

    int arow = t >> 2, aq = t & 3;                       // A stage: 64 rows x 4 chunks of 16 f32
    const float* aptr = x + (size_t)(mt * 64 + arow) * K + k0 + aq * 16;

    float4 qa[4];          // prefetched A (16 f32)
    s16x8  qb[4];          // prefetched B (4 x 8 bf16)

#define LOADA(KT) { const float4* p = (const float4*)(aptr + (KT) * 64); \
                    qa[0] = p[0]; qa[1] = p[1]; qa[2] = p[2]; qa[3] = p[3]; }
#define LOADB(KT) { _Pragma("unroll") for (int jj = 0; jj < 4; ++jj) { \
                    int flat = t + jj * 256; int c = flat >> 3, j = flat & 7; \
                    qb[jj] = *(const s16x8*)(wt + (size_t)c * K + k0 + (KT) * 64 + j * 8); } }

    LOADA(0); LOADB(0);
#pragma unroll 1
    for (int kt = 0; kt < 16; ++kt) {
        // ---- write staged tile to LDS (A converted f32->bf16), swizzled ----
        *(s16x8*)&smem[swzA(arow, aq * 16)]     = cvt8(qa[0], qa[1]);
        *(s16x8*)&smem[swzA(arow, aq * 16 + 8)] = cvt8(qa[2], qa[3]);
#pragma unroll
        for (int jj = 0; jj < 4; ++jj) {
            int flat = t + jj * 256;
            int c = flat >> 3, j = flat & 7;
            *(s16x8*)&smem[swzB(c, j * 8)] = qb[jj];
        }
        __syncthreads();
        // ---- issue next tile's loads (latency hides under MFMA + other waves) ----
        if (kt < 15) { LOADA(kt + 1); LOADB(kt + 1); }
        // ---- compute: 16 MFMA per wave ----
#pragma unroll
        for (int kk = 0; kk < 2; ++kk) {
            int kb = kk * 32 + l4 * 8;
            s16x8 a[2], b[4];
#pragma unroll
            for (int m = 0; m < 2; ++m)
                a[m] = *(const s16x8*)&smem[swzA(wm * 32 + m * 16 + l15, kb)];
#pragma unroll
            for (int n = 0; n < 4; ++n)
                b[n] = *(const s16x8*)&smem[swzB(wn * 64 + n * 16 + l15, kb)];
#pragma unroll
            for (int m = 0; m < 2; ++m)
#pragma unroll
                for (int n = 0; n < 4; ++n)
                    acc[m][n] = __builtin_amdgcn_mfma_f32_16x16x32_bf16(a[m], b[n], acc[m][n], 0, 0, 0);
        }
        __syncthreads();
    }
#undef LOADA
#undef LOADB
    // ---- epilogue: accumulate partial tile. D layout col=lane&15, row=(lane>>4)*4+j ----
#pragma unroll
    for (int m = 0; m < 2; ++m)
#pragma unroll
        for (int n = 0; n < 4; ++n) {
            int col  = wn * 64 + n * 16 + l15;
            int row0 = mt * 64 + wm * 32 + m * 16 + l4 * 4;
#pragma unroll
            for (int j = 0; j < 4; ++j)
                unsafeAtomicAdd(&h[(size_t)(row0 + j) * DOUT + col], acc[m][n][j]);
        }
}

// ---------------- K7: CSR gather + self loop + bias + relu ----------------
__global__ __launch_bounds__(256) void k_gather(const float* __restrict__ ws,
                                                const float* __restrict__ bc, const float* __restrict__ bd,
                                                float* __restrict__ out) {
    int wv = threadIdx.x >> 6, lane = threadIdx.x & 63;
    int g = blockIdx.x * 4 + wv;
    const float* h; const int* srow; const float* scoef; const int* start; const float* dinv;
    const float* bvec; float* outp; int node;
    if (g < N_CELL) {
        node = g; h = ws + OFF_H_C; srow = (const int*)(ws + OFF_SROW_C); scoef = ws + OFF_SCOEF_C;
        start = (const int*)(ws + OFF_START_C); dinv = ws + OFF_DEG_C; bvec = bc; outp = out;
    } else {
        node = g - N_CELL; if (node >= N_DRUG) return;
        h = ws + OFF_H_D; srow = (const int*)(ws + OFF_SROW_D); scoef = ws + OFF_SCOEF_D;
        start = (const int*)(ws + OFF_START_D); dinv = ws + OFF_DEG_D; bvec = bd;
        outp = out + (size_t)N_CELL * DOUT;
    }
    float di = dinv[node], sc = di * di;
    float2 v = ((const float2*)(h + (size_t)node * DOUT))[lane];
    float ax = sc * v.x, ay = sc * v.y;
    int s0 = start[node], s1 = start[node + 1];
    int e = s0;
    for (; e + 1 < s1; e += 2) {
        int r0 = srow[e];     float c0 = scoef[e];
        int r1 = srow[e + 1]; float c1 = scoef[e + 1];
        float2 u0 = ((const float2*)(h + (size_t)r0 * DOUT))[lane];
        float2 u1 = ((const float2*)(h + (size_t)r1 * DOUT))[lane];
        ax += c0 * u0.x + c1 * u1.x;
        ay += c0 * u0.y + c1 * u1.y;
    }
    if (e < s1) {
        int r = srow[e]; float cf = scoef[e];
        float2 u = ((const float2*)(h + (size_t)r * DOUT))[lane];
        ax += cf * u.x; ay += cf * u.y;
    }
    float2 bb = ((const float2*)bvec)[lane];
    ax = fmaxf(ax + bb.x, 0.f);
    ay = fmaxf(ay + bb.y, 0.f);
    float2 o; o.x = ax; o.y = ay;
    ((float2*)outp)[(size_t)node * 64 + lane] = o;
}

// ---------------- host ----------------
extern "C" void kernel_launch(void* const* d_in, const int* in_sizes, int n_in,
                              void* d_out, int out_size, void* d_ws, size_t ws_size,
                              hipStream_t stream) {
    const float* cell_feat = (const float*)d_in[0];
    const int*   cell_edge = (const int*)d_in[1];
    const float* W_cell    = (const float*)d_in[2];
    const float* b_cell    = (const float*)d_in[3];
    const float* drug_feat = (const float*)d_in[4];
    const int*   drug_edge = (const int*)d_in[5];
    const float* W_drug    = (const float*)d_in[6];
    const float* b_drug    = (const float*)d_in[7];
    float* out = (float*)d_out;
    float* ws  = (float*)d_ws;
    unsigned short* wtc = (unsigned short*)((char*)d_ws + WT_C_BYTE);
    unsigned short* wtd = (unsigned short*)((char*)d_ws + WT_D_BYTE);

    k_init<<<144, 256, 0, stream>>>(ws);
    k_zero<<<1536, 256, 0, stream>>>(ws);   // zero h (gemm accumulates atomically)
    k_edge<<<(E_CELL + E_DRUG) / 256, 256, 0, stream>>>(cell_feat, cell_edge, drug_feat, drug_edge, ws);
    k_dinv<<<48, 256, 0, stream>>>(ws);
    k_scan<<<2, 256, 0, stream>>>(ws);
    k_wt<<<1536, 256, 0, stream>>>(W_cell, W_drug, wtc, wtd);
    k_fill<<<1536, 256, 0, stream>>>(cell_edge, drug_edge, ws);
    k_gemm<<<1280, 256, 0, stream>>>(cell_feat, drug_feat, wtc, wtd, ws);
    k_gather<<<3072, 256, 0, stream>>>(ws, b_cell, b_drug, out);
}